// Round 3
// baseline (381.143 us; speedup 1.0000x reference)
//
#include <hip/hip_runtime.h>

// Emission-absorption volume renderer. fp32 in/out.
// Outputs flat: [features(3NR) | depths(NR) | opac(NR) | weights(128NR)].
//
// R7: LDS-staged feats. rocprof R6: VGPR=32 (compiler serialized the 10
// per-lane loads), VALU 9.4%, HBM 24%, dur identical to the 64-lane/ray
// version at matched per-ray TRANSACTION count -> theory: bound on cache
// line transactions, not bytes. feats (60% of input bytes) was read at
// 96B-stride dwordx4 = ~4.4x line-touch amplification.
// Fix: block-coalesced feats staging (6x dwordx4 per thread at block
// stride = 4KB contiguous per instr) into 24.25KB LDS, per-lane b128
// reads (ray pad +4 words -> even bank slots). launch_bounds(256,4)
// lets staging + dens/lens loads all stay in flight; weight math (scan,
// exp) runs under the feats latency before the barrier.
//
// NUMERICAL NOTE (R3): the sample-127 sentinel delta (1e10) must NOT
// enter the prefix scan (fp32 cancellation corrupts absorption near ray
// end). It only feeds the final opacity, where exp(-~1e10) == 0.

#define BG_OPACITY_F 1e10f

typedef float floatx4 __attribute__((ext_vector_type(4)));

#define RSTRIDE 388   // LDS words per ray: 384 + 4 pad (even 4-bank slots)

__global__ __launch_bounds__(256, 4) void ea_render_kernel(
    const float* __restrict__ dens,    // (rays, 128)
    const float* __restrict__ feats,   // (rays, 128, 3)
    const float* __restrict__ lens,    // (rays, 128)
    const float* __restrict__ dirs,    // (rays, 3)
    float* __restrict__ out_feat,      // (rays, 3)
    float* __restrict__ out_depth,     // (rays)
    float* __restrict__ out_opac,      // (rays)
    float* __restrict__ out_w,         // (rays, 128)
    int n_rays)
{
    __shared__ __align__(16) float sfeat[16 * RSTRIDE];   // 24832 B

    const int tid  = threadIdx.x;
    const int lane = tid & 63;
    const int t    = lane & 15;                  // sub-lane within ray group
    const int rb   = tid >> 4;                   // ray index within block 0..15
    const long ray0 = (long)blockIdx.x * 16;
    // Clamp (no early return: block has a barrier). Tail duplicates write
    // identical values to identical addresses - benign.
    const long ray = (ray0 + rb < n_rays) ? (ray0 + rb) : (n_rays - 1);

    const long base = ray * 128;
    const int  n0   = t * 8;                     // first sample owned

    // ---- issue feats staging loads FIRST: block-coalesced, 4KB/instr ----
    const float* fblock = feats + ray0 * 384;    // this block's 16 rays
    float4 fc[6];
    #pragma unroll
    for (int k = 0; k < 6; ++k) {
        const int c = k * 256 + tid;             // 16B chunk id, 0..1535
        const bool ok = (ray0 + c / 96) < n_rays;
        fc[k] = ok ? *(const float4*)(fblock + (long)c * 4)
                   : make_float4(0.f, 0.f, 0.f, 0.f);
    }

    // ---- per-lane dens/lens loads (32B stride, 2x amplification, ok) ----
    const float4 dA = *(const float4*)(dens + base + n0);
    const float4 dB = *(const float4*)(dens + base + n0 + 4);
    const float4 lA = *(const float4*)(lens + base + n0);
    const float4 lB = *(const float4*)(lens + base + n0 + 4);

    const float* dp = dirs + ray * 3;            // 12B broadcast per group
    const float dx = dp[0], dy = dp[1], dz = dp[2];
    const float dn = sqrtf(dx * dx + dy * dy + dz * dz);

    const float l[8]  = {lA.x, lA.y, lA.z, lA.w, lB.x, lB.y, lB.z, lB.w};
    const float dv[8] = {dA.x, dA.y, dA.z, dA.w, dB.x, dB.y, dB.z, dB.w};

    // l[0] of sub-lane t+1 (delta of our last sample). At t==15 this
    // crosses into the next ray's group - unused there (sentinel).
    const float lnext = __shfl_down(lA.x, 1, 64);

    // ---- weighted = delta * dir_norm * relu(dens) ----
    float w[8];
    #pragma unroll
    for (int i = 0; i < 7; ++i)
        w[i] = (l[i + 1] - l[i]) * dn * fmaxf(dv[i], 0.0f);
    const float delta7 = (t == 15) ? BG_OPACITY_F : (lnext - l[7]);
    w[7] = delta7 * dn * fmaxf(dv[7], 0.0f);
    const float w7s = (t == 15) ? 0.0f : w[7];   // sentinel excluded

    const float s = w[0] + w[1] + w[2] + w[3] + w[4] + w[5] + w[6] + w7s;

    // ---- 16-lane inclusive scan of per-lane sums (4 dependent steps) ----
    float inc = s;
    #pragma unroll
    for (int off = 1; off < 16; off <<= 1) {
        const float u = __shfl_up(inc, off, 64);
        if (t >= off) inc += u;                  // t-mask keeps groups apart
    }
    const float excl = inc - s;                  // sum over all n < n0

    // ---- weights: wgt[i] = (1 - exp(-w[i])) * exp(-prefix_excl[i]) ----
    float a = __expf(-excl);
    float wgt[8];
    #pragma unroll
    for (int i = 0; i < 8; ++i) {
        const float ei = __expf(-w[i]);          // t==15,i==7: exp(-1e10)=0
        wgt[i] = (1.0f - ei) * a;
        a *= ei;
    }

    // ---- weights out (streamed, never re-read -> nontemporal) ----
    const floatx4 wv0 = {wgt[0], wgt[1], wgt[2], wgt[3]};
    const floatx4 wv1 = {wgt[4], wgt[5], wgt[6], wgt[7]};
    __builtin_nontemporal_store(wv0, (floatx4*)(out_w + base + n0));
    __builtin_nontemporal_store(wv1, (floatx4*)(out_w + base + n0 + 4));

    if (t == 15) {
        // inc == total real weighted; re-add sentinel term for opacity.
        out_opac[ray] = 1.0f - __expf(-(inc + w[7]));
    }

    // ---- now land the staged feats into LDS ----
    // chunk c -> ray r = c/96, lane t' = (c%96)/6, word i' = (c%96)%6.
    // (16B chunks never straddle a 24-word lane region: both 4-aligned.)
    #pragma unroll
    for (int k = 0; k < 6; ++k) {
        const int c   = k * 256 + tid;
        const int r   = c / 96;
        const int rem = c - r * 96;
        const int tq  = rem / 6;
        const int iq  = rem - tq * 6;
        *(float4*)&sfeat[r * RSTRIDE + tq * 24 + iq * 4] = fc[k];
    }
    __syncthreads();

    // ---- per-lane feats from LDS: 6 x b128, contiguous 96B region ----
    const float* myf = &sfeat[rb * RSTRIDE + t * 24];
    const float4 q0 = *(const float4*)(myf +  0);
    const float4 q1 = *(const float4*)(myf +  4);
    const float4 q2 = *(const float4*)(myf +  8);
    const float4 q3 = *(const float4*)(myf + 12);
    const float4 q4 = *(const float4*)(myf + 16);
    const float4 q5 = *(const float4*)(myf + 20);
    const float f[24] = {q0.x, q0.y, q0.z, q0.w, q1.x, q1.y, q1.z, q1.w,
                         q2.x, q2.y, q2.z, q2.w, q3.x, q3.y, q3.z, q3.w,
                         q4.x, q4.y, q4.z, q4.w, q5.x, q5.y, q5.z, q5.w};

    float pd = 0.0f, fr = 0.0f, fg = 0.0f, fb = 0.0f;
    #pragma unroll
    for (int i = 0; i < 8; ++i) {
        pd += wgt[i] * l[i];
        fr += wgt[i] * f[3 * i + 0];
        fg += wgt[i] * f[3 * i + 1];
        fb += wgt[i] * f[3 * i + 2];
    }

    // ---- 16-lane butterfly reductions (xor stays within group) ----
    #pragma unroll
    for (int off = 8; off; off >>= 1) {
        pd += __shfl_xor(pd, off, 64);
        fr += __shfl_xor(fr, off, 64);
        fg += __shfl_xor(fg, off, 64);
        fb += __shfl_xor(fb, off, 64);
    }

    if (t == 0) {
        // features += (1 - opac) * BG_COLOR with BG_COLOR == 0 -> no-op
        out_feat[ray * 3 + 0] = fr;
        out_feat[ray * 3 + 1] = fg;
        out_feat[ray * 3 + 2] = fb;
        out_depth[ray] = pd;
    }
}

extern "C" void kernel_launch(void* const* d_in, const int* in_sizes, int n_in,
                              void* d_out, int out_size, void* d_ws, size_t ws_size,
                              hipStream_t stream) {
    // Input order verified (R4 decode): dens(0), feats(1), lens(2), dirs(3).
    const float* dens  = (const float*)d_in[0];  // (B,R,N,1)
    const float* feats = (const float*)d_in[1];  // (B,R,N,3)
    const float* lens  = (const float*)d_in[2];  // (B,R,N)
    const float* dirs  = (const float*)d_in[3];  // (B,R,3)

    const int n_rays = in_sizes[3] / 3;          // B*R = 131072

    float* out = (float*)d_out;
    float* out_feat  = out;                       // (rays, 3)
    float* out_depth = out + (long)n_rays * 3;    // (rays, 1)
    float* out_opac  = out + (long)n_rays * 4;    // (rays, 1)
    float* out_w     = out + (long)n_rays * 5;    // (rays, 128)

    const int blocks = (n_rays + 15) / 16;        // 16 rays (4 waves) / block
    ea_render_kernel<<<blocks, 256, 0, stream>>>(
        dens, feats, lens, dirs, out_feat, out_depth, out_opac, out_w, n_rays);
}